// Round 13
// baseline (170.996 us; speedup 1.0000x reference)
//
#include <hip/hip_runtime.h>
#include <hip/hip_bf16.h>
#include <math.h>

#define N_NODES   100000
#define IN_DIM    256
#define HIDDEN    512
#define N_INC     1000000
#define N_SEG     100000

typedef __attribute__((ext_vector_type(8))) short bf16x8;
typedef __attribute__((ext_vector_type(4))) float f32x4;

__device__ __forceinline__ unsigned short f2bf(float f) {
  unsigned int u = __builtin_bit_cast(unsigned int, f);
  u += 0x7FFFu + ((u >> 16) & 1u);   // RNE
  return (unsigned short)(u >> 16);
}
__device__ __forceinline__ float bflo(unsigned int u) {   // low bf16 -> f32
  return __builtin_bit_cast(float, u << 16);
}
__device__ __forceinline__ float bfhi(unsigned int u) {   // high bf16 -> f32
  return __builtin_bit_cast(float, u & 0xFFFF0000u);
}
__device__ __forceinline__ unsigned pack2(float a, float b) {
  return (unsigned)f2bf(a) | ((unsigned)f2bf(b) << 16);
}

// async global->LDS DMA, 16 B per lane (1 KB per wave-instruction).
// LDS dest must be wave-uniform base + lane*16; global src may be per-lane.
__device__ __forceinline__ void gload_lds16(const void* g, void* l) {
  __builtin_amdgcn_global_load_lds(
      (const __attribute__((address_space(1))) unsigned int*)g,
      (__attribute__((address_space(3))) unsigned int*)l, 16, 0, 0);
}

#define XBF_BLOCKS    25000   // N_NODES*IN_DIM/4 float4s / 256 threads
#define STARTS_BLOCKS 391     // ceil((N_SEG+1)/256)
#define W1T_BLOCKS    128     // 32768 float4s / 256

// ---------------- kernel 1: fused prep (xbf | seg_starts | w1t by block role) ----------
__global__ void k_prep(const float* __restrict__ x, unsigned short* __restrict__ xb,
                       const int* __restrict__ ids, int* __restrict__ starts,
                       const float* __restrict__ W1, unsigned short* __restrict__ W1t) {
  const int b = blockIdx.x;
  const int tid = threadIdx.x;
  if (b < XBF_BLOCKS) {
    // x f32 -> xb bf16 (halves gather bytes)
    size_t idx = (size_t)b * 256 + tid;          // one float4 -> uint2 each
    float4 v = *(const float4*)(x + idx * 4);
    uint2 p;
    p.x = pack2(v.x, v.y);
    p.y = pack2(v.z, v.w);
    *(uint2*)(xb + idx * 4) = p;
  } else if (b < XBF_BLOCKS + STARTS_BLOCKS) {
    // starts[s] = first i with ids[i] >= s (ids sorted); starts[N_SEG] = N_INC
    int s = (b - XBF_BLOCKS) * 256 + tid;
    if (s > N_SEG) return;
    int lo = 0, hi = N_INC;
    while (lo < hi) {
      int mid = (lo + hi) >> 1;
      if (ids[mid] < s) lo = mid + 1; else hi = mid;
    }
    starts[s] = lo;
  } else {
    // W1 f32[256][512] -> W1t bf16[512][256]
    int idx = (b - XBF_BLOCKS - STARTS_BLOCKS) * 256 + tid;   // 0..32767
    int k  = idx >> 7;                           // 0..255
    int c4 = idx & 127;                          // float4 index along HIDDEN
    float4 v = *(const float4*)(W1 + (size_t)k * HIDDEN + c4 * 4);
    W1t[(c4 * 4 + 0) * IN_DIM + k] = f2bf(v.x);
    W1t[(c4 * 4 + 1) * IN_DIM + k] = f2bf(v.y);
    W1t[(c4 * 4 + 2) * IN_DIM + k] = f2bf(v.z);
    W1t[(c4 * 4 + 3) * IN_DIM + k] = f2bf(v.w);
  }
}

// ---------------- kernel 2: gather(bf16) + segment sum -> Zb bf16 ----------------
// Split-row: lanes 0-31 even incidences, lanes 32-63 odd; 16 B/lane (uint4) so one
// wave instruction covers TWO 512 B rows. Halves combined via shfl_xor(32).
// Pinned at the ~7.3 TB/s fabric/L3 roofline (rounds 3/4/7/8 all converge here).
#define ACC8(v)                                                        \
  acc0 += bflo((v).x); acc1 += bfhi((v).x);                            \
  acc2 += bflo((v).y); acc3 += bfhi((v).y);                            \
  acc4 += bflo((v).z); acc5 += bfhi((v).z);                            \
  acc6 += bflo((v).w); acc7 += bfhi((v).w);

__global__ void k_segsum(const unsigned short* __restrict__ xb, const int* __restrict__ nodes,
                         const int* __restrict__ starts, unsigned short* __restrict__ Zb) {
  int wave = threadIdx.x >> 6;
  int lane = threadIdx.x & 63;
  int s = blockIdx.x * 4 + wave;
  if (s >= N_SEG) return;
  const int beg = starts[s];
  const int end = starts[s + 1];
  const int half = lane >> 5;
  const int sl   = lane & 31;
  const unsigned short* base = xb + sl * 8;    // this lane's 16B slice within any row
  float acc0 = 0.f, acc1 = 0.f, acc2 = 0.f, acc3 = 0.f;
  float acc4 = 0.f, acc5 = 0.f, acc6 = 0.f, acc7 = 0.f;
  int j = beg + half;
  for (; j + 6 < end; j += 8) {               // 4 rows per half per iter
    int n0 = nodes[j], n1 = nodes[j + 2], n2 = nodes[j + 4], n3 = nodes[j + 6];
    uint4 v0 = *(const uint4*)(base + (size_t)n0 * IN_DIM);
    uint4 v1 = *(const uint4*)(base + (size_t)n1 * IN_DIM);
    uint4 v2 = *(const uint4*)(base + (size_t)n2 * IN_DIM);
    uint4 v3 = *(const uint4*)(base + (size_t)n3 * IN_DIM);
    ACC8(v0); ACC8(v1); ACC8(v2); ACC8(v3);
  }
  for (; j < end; j += 2) {
    int n0 = nodes[j];
    uint4 v0 = *(const uint4*)(base + (size_t)n0 * IN_DIM);
    ACC8(v0);
  }
  acc0 += __shfl_xor(acc0, 32, 64);
  acc1 += __shfl_xor(acc1, 32, 64);
  acc2 += __shfl_xor(acc2, 32, 64);
  acc3 += __shfl_xor(acc3, 32, 64);
  acc4 += __shfl_xor(acc4, 32, 64);
  acc5 += __shfl_xor(acc5, 32, 64);
  acc6 += __shfl_xor(acc6, 32, 64);
  acc7 += __shfl_xor(acc7, 32, 64);
  if (half == 0) {
    uint4 p;
    p.x = pack2(acc0, acc1);
    p.y = pack2(acc2, acc3);
    p.z = pack2(acc4, acc5);
    p.w = pack2(acc6, acc7);
    *(uint4*)(Zb + (size_t)s * IN_DIM + sl * 8) = p;
  }
}

// ---------------- kernel 3: MFMA MLP v6 — batched staging, 2 drains total ----------
// Block: 256 thr / 4 waves; block tile 256 rows; wave tile 64 rows x 512 cols.
// A in registers (a[4][8] uint4, full K=256). B staged in TWO halves of 4 nt-tiles
// each (128 KB LDS): per half, each wave issues 32 async global_load_lds (16 B/lane)
// and ONE barrier drains them -> 2 stage-drains per block instead of 8.
// 1 block/CU (LDS-bound); grid 391 ~ 1.5 scheduling rounds.
// C/D layout (m89-verified): col = lane&15, row = (lane>>4)*4 + e.
__global__ __launch_bounds__(256, 1) void k_mlp(
    const unsigned short* __restrict__ Zb, const unsigned short* __restrict__ W1t,
    const float* __restrict__ b1, const float* __restrict__ W2,
    const float* __restrict__ b2, float* __restrict__ out) {
  __shared__ __align__(16) unsigned short Bf2[4][8][4][64][8];  // [ntl][kc][cf][lane][e] 128 KB
  const int tid  = threadIdx.x;
  const int wave = tid >> 6;
  const int lane = tid & 63;
  const int m0   = blockIdx.x * 256 + wave * 64;

  // A fragments: a[rf][kc], lane l holds Z[m0+rf*16+(l&15)][kc*32+(l>>4)*8 ..+8]
  uint4 a[4][8];
  const int arow = m0 + (lane & 15);
  const int ak   = (lane >> 4) * 8;
  #pragma unroll
  for (int kc = 0; kc < 8; ++kc) {
    #pragma unroll
    for (int rf = 0; rf < 4; ++rf) {
      int row = arow + rf * 16;
      if (row < N_SEG)
        a[rf][kc] = *(const uint4*)(Zb + (size_t)row * IN_DIM + kc * 32 + ak);
      else
        a[rf][kc] = make_uint4(0u, 0u, 0u, 0u);
    }
  }

  // per-lane global source base for B staging: col = c0 + wave*16 + (lane&15),
  // kk = it*32 + (lane>>4)*8
  const unsigned short* wsrc = W1t + (size_t)(wave * 16 + (lane & 15)) * IN_DIM
                                   + (lane >> 4) * 8;

  float logit[4][4];
  #pragma unroll
  for (int rf = 0; rf < 4; ++rf)
    #pragma unroll
    for (int e = 0; e < 4; ++e) logit[rf][e] = 0.f;

  for (int half = 0; half < 2; ++half) {
    // ---- stage 4 nt-tiles (32 DMAs/wave, all in flight) ----
    #pragma unroll
    for (int ntl = 0; ntl < 4; ++ntl) {
      const size_t csrc = (size_t)(half * 4 + ntl) * 64 * IN_DIM;
      #pragma unroll
      for (int it = 0; it < 8; ++it)
        gload_lds16(wsrc + csrc + it * 32, &Bf2[ntl][it][wave][lane][0]);
    }
    __syncthreads();   // single drain for all 32 DMAs

    // ---- compute 4 nt-tiles ----
    #pragma unroll
    for (int ntl = 0; ntl < 4; ++ntl) {
      const int c0 = (half * 4 + ntl) * 64;
      f32x4 acc[4][4];
      #pragma unroll
      for (int rf = 0; rf < 4; ++rf)
        #pragma unroll
        for (int cf = 0; cf < 4; ++cf) acc[rf][cf] = (f32x4){0.f, 0.f, 0.f, 0.f};

      #pragma unroll
      for (int kc = 0; kc < 8; ++kc) {
        #pragma unroll
        for (int cf = 0; cf < 4; ++cf) {
          bf16x8 bv = *(const bf16x8*)&Bf2[ntl][kc][cf][lane][0];
          #pragma unroll
          for (int rf = 0; rf < 4; ++rf) {
            bf16x8 av = __builtin_bit_cast(bf16x8, a[rf][kc]);
            acc[rf][cf] = __builtin_amdgcn_mfma_f32_16x16x32_bf16(av, bv, acc[rf][cf], 0, 0, 0);
          }
        }
      }
      // epilogue for this 64-col tile: bias + relu + dot with W2
      #pragma unroll
      for (int cf = 0; cf < 4; ++cf) {
        int cc = c0 + cf * 16 + (lane & 15);
        float bb = b1[cc];
        float w2 = W2[cc];
        #pragma unroll
        for (int rf = 0; rf < 4; ++rf)
          #pragma unroll
          for (int e = 0; e < 4; ++e) {
            float h = acc[rf][cf][e] + bb;
            h = h > 0.f ? h : 0.f;
            logit[rf][e] = fmaf(h, w2, logit[rf][e]);
          }
      }
    }
    __syncthreads();   // all waves done reading before next half's restage
  }
  // reduce over the 16 lanes of each column group (lane&15)
  #pragma unroll
  for (int rf = 0; rf < 4; ++rf)
    #pragma unroll
    for (int e = 0; e < 4; ++e) {
      float v = logit[rf][e];
      v += __shfl_xor(v, 1, 64);
      v += __shfl_xor(v, 2, 64);
      v += __shfl_xor(v, 4, 64);
      v += __shfl_xor(v, 8, 64);
      logit[rf][e] = v;
    }
  if ((lane & 15) == 0) {
    float bb2 = b2[0];
    #pragma unroll
    for (int rf = 0; rf < 4; ++rf)
      #pragma unroll
      for (int e = 0; e < 4; ++e) {
        int row = m0 + rf * 16 + (lane >> 4) * 4 + e;
        if (row < N_SEG)
          out[row] = 1.f / (1.f + expf(-(logit[rf][e] + bb2)));
      }
  }
}

extern "C" void kernel_launch(void* const* d_in, const int* in_sizes, int n_in,
                              void* d_out, int out_size, void* d_ws, size_t ws_size,
                              hipStream_t stream) {
  const float* x   = (const float*)d_in[0];
  const int* nodes = (const int*)d_in[1];
  const int* ids   = (const int*)d_in[2];
  const float* W1  = (const float*)d_in[4];
  const float* b1  = (const float*)d_in[5];
  const float* W2  = (const float*)d_in[6];
  const float* b2  = (const float*)d_in[7];
  float* out       = (float*)d_out;

  char* ws = (char*)d_ws;
  int* starts = (int*)ws;                                        // (N_SEG+1)*4 B
  size_t off = (((size_t)(N_SEG + 1) * sizeof(int)) + 1023) & ~(size_t)1023;
  unsigned short* Zb = (unsigned short*)(ws + off);              // 51.2 MB
  off += (size_t)N_NODES * IN_DIM * sizeof(unsigned short);
  off = (off + 1023) & ~(size_t)1023;
  unsigned short* W1t = (unsigned short*)(ws + off);             // 256 KB
  off += (size_t)HIDDEN * IN_DIM * sizeof(unsigned short);
  off = (off + 1023) & ~(size_t)1023;
  unsigned short* xb = (unsigned short*)(ws + off);              // 51.2 MB

  k_prep<<<XBF_BLOCKS + STARTS_BLOCKS + W1T_BLOCKS, 256, 0, stream>>>(
      x, xb, ids, starts, W1, W1t);
  k_segsum<<<(N_SEG + 3) / 4, 256, 0, stream>>>(xb, nodes, starts, Zb);
  k_mlp<<<(N_SEG + 255) / 256, 256, 0, stream>>>(Zb, W1t, b1, W2, b2, out);
}

// Round 14
// 169.119 us; speedup vs baseline: 1.0111x; 1.0111x over previous
//
#include <hip/hip_runtime.h>
#include <hip/hip_bf16.h>
#include <math.h>

#define N_NODES   100000
#define IN_DIM    256
#define HIDDEN    512
#define N_INC     1000000
#define N_SEG     100000

typedef __attribute__((ext_vector_type(8))) short bf16x8;
typedef __attribute__((ext_vector_type(4))) float f32x4;

__device__ __forceinline__ unsigned short f2bf(float f) {
  unsigned int u = __builtin_bit_cast(unsigned int, f);
  u += 0x7FFFu + ((u >> 16) & 1u);   // RNE
  return (unsigned short)(u >> 16);
}
__device__ __forceinline__ float bflo(unsigned int u) {   // low bf16 -> f32
  return __builtin_bit_cast(float, u << 16);
}
__device__ __forceinline__ float bfhi(unsigned int u) {   // high bf16 -> f32
  return __builtin_bit_cast(float, u & 0xFFFF0000u);
}
__device__ __forceinline__ unsigned pack2(float a, float b) {
  return (unsigned)f2bf(a) | ((unsigned)f2bf(b) << 16);
}

// async global->LDS DMA, 16 B per lane (1 KB per wave-instruction).
// LDS dest must be wave-uniform base + lane*16; global src may be per-lane.
__device__ __forceinline__ void gload_lds16(const void* g, void* l) {
  __builtin_amdgcn_global_load_lds(
      (const __attribute__((address_space(1))) unsigned int*)g,
      (__attribute__((address_space(3))) unsigned int*)l, 16, 0, 0);
}

#define XBF_BLOCKS    25000   // N_NODES*IN_DIM/4 float4s / 256 threads
#define STARTS_BLOCKS 391     // ceil((N_SEG+1)/256)
#define W1T_BLOCKS    128     // 32768 float4s / 256

// ---------------- kernel 1: fused prep (xbf | seg_starts | w1t by block role) ----------
__global__ void k_prep(const float* __restrict__ x, unsigned short* __restrict__ xb,
                       const int* __restrict__ ids, int* __restrict__ starts,
                       const float* __restrict__ W1, unsigned short* __restrict__ W1t) {
  const int b = blockIdx.x;
  const int tid = threadIdx.x;
  if (b < XBF_BLOCKS) {
    // x f32 -> xb bf16 (halves gather bytes)
    size_t idx = (size_t)b * 256 + tid;          // one float4 -> uint2 each
    float4 v = *(const float4*)(x + idx * 4);
    uint2 p;
    p.x = pack2(v.x, v.y);
    p.y = pack2(v.z, v.w);
    *(uint2*)(xb + idx * 4) = p;
  } else if (b < XBF_BLOCKS + STARTS_BLOCKS) {
    // starts[s] = first i with ids[i] >= s (ids sorted); starts[N_SEG] = N_INC
    int s = (b - XBF_BLOCKS) * 256 + tid;
    if (s > N_SEG) return;
    int lo = 0, hi = N_INC;
    while (lo < hi) {
      int mid = (lo + hi) >> 1;
      if (ids[mid] < s) lo = mid + 1; else hi = mid;
    }
    starts[s] = lo;
  } else {
    // W1 f32[256][512] -> W1t bf16[512][256]
    int idx = (b - XBF_BLOCKS - STARTS_BLOCKS) * 256 + tid;   // 0..32767
    int k  = idx >> 7;                           // 0..255
    int c4 = idx & 127;                          // float4 index along HIDDEN
    float4 v = *(const float4*)(W1 + (size_t)k * HIDDEN + c4 * 4);
    W1t[(c4 * 4 + 0) * IN_DIM + k] = f2bf(v.x);
    W1t[(c4 * 4 + 1) * IN_DIM + k] = f2bf(v.y);
    W1t[(c4 * 4 + 2) * IN_DIM + k] = f2bf(v.z);
    W1t[(c4 * 4 + 3) * IN_DIM + k] = f2bf(v.w);
  }
}

// ---------------- kernel 2: gather(bf16) + segment sum -> Zb bf16 ----------------
// Split-row: lanes 0-31 even incidences, lanes 32-63 odd; 16 B/lane (uint4) so one
// wave instruction covers TWO 512 B rows. Halves combined via shfl_xor(32).
// Pinned at the ~7.3 TB/s fabric/L3 roofline (rounds 3/4/7/8 all converge here).
#define ACC8(v)                                                        \
  acc0 += bflo((v).x); acc1 += bfhi((v).x);                            \
  acc2 += bflo((v).y); acc3 += bfhi((v).y);                            \
  acc4 += bflo((v).z); acc5 += bfhi((v).z);                            \
  acc6 += bflo((v).w); acc7 += bfhi((v).w);

__global__ void k_segsum(const unsigned short* __restrict__ xb, const int* __restrict__ nodes,
                         const int* __restrict__ starts, unsigned short* __restrict__ Zb) {
  int wave = threadIdx.x >> 6;
  int lane = threadIdx.x & 63;
  int s = blockIdx.x * 4 + wave;
  if (s >= N_SEG) return;
  const int beg = starts[s];
  const int end = starts[s + 1];
  const int half = lane >> 5;
  const int sl   = lane & 31;
  const unsigned short* base = xb + sl * 8;    // this lane's 16B slice within any row
  float acc0 = 0.f, acc1 = 0.f, acc2 = 0.f, acc3 = 0.f;
  float acc4 = 0.f, acc5 = 0.f, acc6 = 0.f, acc7 = 0.f;
  int j = beg + half;
  for (; j + 6 < end; j += 8) {               // 4 rows per half per iter
    int n0 = nodes[j], n1 = nodes[j + 2], n2 = nodes[j + 4], n3 = nodes[j + 6];
    uint4 v0 = *(const uint4*)(base + (size_t)n0 * IN_DIM);
    uint4 v1 = *(const uint4*)(base + (size_t)n1 * IN_DIM);
    uint4 v2 = *(const uint4*)(base + (size_t)n2 * IN_DIM);
    uint4 v3 = *(const uint4*)(base + (size_t)n3 * IN_DIM);
    ACC8(v0); ACC8(v1); ACC8(v2); ACC8(v3);
  }
  for (; j < end; j += 2) {
    int n0 = nodes[j];
    uint4 v0 = *(const uint4*)(base + (size_t)n0 * IN_DIM);
    ACC8(v0);
  }
  acc0 += __shfl_xor(acc0, 32, 64);
  acc1 += __shfl_xor(acc1, 32, 64);
  acc2 += __shfl_xor(acc2, 32, 64);
  acc3 += __shfl_xor(acc3, 32, 64);
  acc4 += __shfl_xor(acc4, 32, 64);
  acc5 += __shfl_xor(acc5, 32, 64);
  acc6 += __shfl_xor(acc6, 32, 64);
  acc7 += __shfl_xor(acc7, 32, 64);
  if (half == 0) {
    uint4 p;
    p.x = pack2(acc0, acc1);
    p.y = pack2(acc2, acc3);
    p.z = pack2(acc4, acc5);
    p.w = pack2(acc6, acc7);
    *(uint4*)(Zb + (size_t)s * IN_DIM + sl * 8) = p;
  }
}

// ---------------- kernel 3: MFMA MLP v7 — DMA staging + high co-residency ----------
// Block: 256 thr / 4 waves, 128 rows/block (32 rows/wave, rf=2) -> grid 782.
// __launch_bounds__(256,3): VGPR cap 170 (est ~130, no spill), LDS 32 KB -> 3
// blocks/CU co-resident (12 waves/CU) so other blocks' MFMAs cover each block's
// stage-drain and A-load latency (m114 overlap). B staged via global_load_lds
// (16 B/lane, fire-and-forget, 8 DMAs/wave/nt, one barrier drain).
// C/D layout (m89-verified): col = lane&15, row = (lane>>4)*4 + e.
__global__ __launch_bounds__(256, 3) void k_mlp(
    const unsigned short* __restrict__ Zb, const unsigned short* __restrict__ W1t,
    const float* __restrict__ b1, const float* __restrict__ W2,
    const float* __restrict__ b2, float* __restrict__ out) {
  __shared__ __align__(16) unsigned short Bf[8][4][64][8];   // [kc][cf][lane][elem] 32 KB
  const int tid  = threadIdx.x;
  const int wave = tid >> 6;
  const int lane = tid & 63;
  const int m0   = blockIdx.x * 128 + wave * 32;

  // A fragments: a[rf][kc], lane l holds Z[m0+rf*16+(l&15)][kc*32+(l>>4)*8 ..+8]
  uint4 a[2][8];
  const int arow = m0 + (lane & 15);
  const int ak   = (lane >> 4) * 8;
  #pragma unroll
  for (int kc = 0; kc < 8; ++kc) {
    #pragma unroll
    for (int rf = 0; rf < 2; ++rf) {
      int row = arow + rf * 16;
      if (row < N_SEG)
        a[rf][kc] = *(const uint4*)(Zb + (size_t)row * IN_DIM + kc * 32 + ak);
      else
        a[rf][kc] = make_uint4(0u, 0u, 0u, 0u);
    }
  }

  // per-lane global source offset for B staging: col = c0 + wave*16 + (lane&15),
  // kk = kc*32 + (lane>>4)*8
  const unsigned short* wsrc = W1t + (size_t)(wave * 16 + (lane & 15)) * IN_DIM
                                   + (lane >> 4) * 8;

  float logit[2][4];
  #pragma unroll
  for (int rf = 0; rf < 2; ++rf)
    #pragma unroll
    for (int e = 0; e < 4; ++e) logit[rf][e] = 0.f;

  for (int nt = 0; nt < 8; ++nt) {
    const int c0 = nt * 64;
    // stage B via async DMA: per it, this wave fills Bf[it][wave][*][*] (1 KB)
    #pragma unroll
    for (int it = 0; it < 8; ++it)
      gload_lds16(wsrc + (size_t)c0 * IN_DIM + it * 32, &Bf[it][wave][lane][0]);
    __syncthreads();   // drains vmcnt (all 8 DMAs) once

    f32x4 acc[2][4];
    #pragma unroll
    for (int rf = 0; rf < 2; ++rf)
      #pragma unroll
      for (int cf = 0; cf < 4; ++cf) acc[rf][cf] = (f32x4){0.f, 0.f, 0.f, 0.f};

    #pragma unroll
    for (int kc = 0; kc < 8; ++kc) {
      #pragma unroll
      for (int cf = 0; cf < 4; ++cf) {
        bf16x8 bv = *(const bf16x8*)&Bf[kc][cf][lane][0];
        #pragma unroll
        for (int rf = 0; rf < 2; ++rf) {
          bf16x8 av = __builtin_bit_cast(bf16x8, a[rf][kc]);
          acc[rf][cf] = __builtin_amdgcn_mfma_f32_16x16x32_bf16(av, bv, acc[rf][cf], 0, 0, 0);
        }
      }
    }
    __syncthreads();

    // epilogue for this 64-col tile: bias + relu + dot with W2
    #pragma unroll
    for (int cf = 0; cf < 4; ++cf) {
      int cc = c0 + cf * 16 + (lane & 15);
      float bb = b1[cc];
      float w2 = W2[cc];
      #pragma unroll
      for (int rf = 0; rf < 2; ++rf)
        #pragma unroll
        for (int e = 0; e < 4; ++e) {
          float h = acc[rf][cf][e] + bb;
          h = h > 0.f ? h : 0.f;
          logit[rf][e] = fmaf(h, w2, logit[rf][e]);
        }
    }
  }
  // reduce over the 16 lanes of each column group (lane&15)
  #pragma unroll
  for (int rf = 0; rf < 2; ++rf)
    #pragma unroll
    for (int e = 0; e < 4; ++e) {
      float v = logit[rf][e];
      v += __shfl_xor(v, 1, 64);
      v += __shfl_xor(v, 2, 64);
      v += __shfl_xor(v, 4, 64);
      v += __shfl_xor(v, 8, 64);
      logit[rf][e] = v;
    }
  if ((lane & 15) == 0) {
    float bb2 = b2[0];
    #pragma unroll
    for (int rf = 0; rf < 2; ++rf)
      #pragma unroll
      for (int e = 0; e < 4; ++e) {
        int row = m0 + rf * 16 + (lane >> 4) * 4 + e;
        if (row < N_SEG)
          out[row] = 1.f / (1.f + expf(-(logit[rf][e] + bb2)));
      }
  }
}

extern "C" void kernel_launch(void* const* d_in, const int* in_sizes, int n_in,
                              void* d_out, int out_size, void* d_ws, size_t ws_size,
                              hipStream_t stream) {
  const float* x   = (const float*)d_in[0];
  const int* nodes = (const int*)d_in[1];
  const int* ids   = (const int*)d_in[2];
  const float* W1  = (const float*)d_in[4];
  const float* b1  = (const float*)d_in[5];
  const float* W2  = (const float*)d_in[6];
  const float* b2  = (const float*)d_in[7];
  float* out       = (float*)d_out;

  char* ws = (char*)d_ws;
  int* starts = (int*)ws;                                        // (N_SEG+1)*4 B
  size_t off = (((size_t)(N_SEG + 1) * sizeof(int)) + 1023) & ~(size_t)1023;
  unsigned short* Zb = (unsigned short*)(ws + off);              // 51.2 MB
  off += (size_t)N_NODES * IN_DIM * sizeof(unsigned short);
  off = (off + 1023) & ~(size_t)1023;
  unsigned short* W1t = (unsigned short*)(ws + off);             // 256 KB
  off += (size_t)HIDDEN * IN_DIM * sizeof(unsigned short);
  off = (off + 1023) & ~(size_t)1023;
  unsigned short* xb = (unsigned short*)(ws + off);              // 51.2 MB

  k_prep<<<XBF_BLOCKS + STARTS_BLOCKS + W1T_BLOCKS, 256, 0, stream>>>(
      x, xb, ids, starts, W1, W1t);
  k_segsum<<<(N_SEG + 3) / 4, 256, 0, stream>>>(xb, nodes, starts, Zb);
  k_mlp<<<(N_SEG + 127) / 128, 256, 0, stream>>>(Zb, W1t, b1, W2, b2, out);
}

// Round 15
// 151.944 us; speedup vs baseline: 1.1254x; 1.1130x over previous
//
#include <hip/hip_runtime.h>
#include <hip/hip_bf16.h>
#include <math.h>

#define N_NODES   100000
#define IN_DIM    256
#define HIDDEN    512
#define N_INC     1000000
#define N_SEG     100000

typedef __attribute__((ext_vector_type(8))) short bf16x8;
typedef __attribute__((ext_vector_type(4))) float f32x4;

__device__ __forceinline__ unsigned short f2bf(float f) {
  unsigned int u = __builtin_bit_cast(unsigned int, f);
  u += 0x7FFFu + ((u >> 16) & 1u);   // RNE
  return (unsigned short)(u >> 16);
}
__device__ __forceinline__ float bflo(unsigned int u) {   // low bf16 -> f32
  return __builtin_bit_cast(float, u << 16);
}
__device__ __forceinline__ float bfhi(unsigned int u) {   // high bf16 -> f32
  return __builtin_bit_cast(float, u & 0xFFFF0000u);
}
__device__ __forceinline__ unsigned pack2(float a, float b) {
  return (unsigned)f2bf(a) | ((unsigned)f2bf(b) << 16);
}

// async global->LDS DMA, 16 B per lane (1 KB per wave-instruction).
// LDS dest must be wave-uniform base + lane*16; global src may be per-lane.
__device__ __forceinline__ void gload_lds16(const void* g, void* l) {
  __builtin_amdgcn_global_load_lds(
      (const __attribute__((address_space(1))) unsigned int*)g,
      (__attribute__((address_space(3))) unsigned int*)l, 16, 0, 0);
}

#define XBF_BLOCKS    25000   // N_NODES*IN_DIM/4 float4s / 256 threads
#define STARTS_BLOCKS 391     // ceil((N_SEG+1)/256)
#define W1T_BLOCKS    128     // 32768 float4s / 256

// ---------------- kernel 1: fused prep (xbf | seg_starts | w1t by block role) ----------
__global__ void k_prep(const float* __restrict__ x, unsigned short* __restrict__ xb,
                       const int* __restrict__ ids, int* __restrict__ starts,
                       const float* __restrict__ W1, unsigned short* __restrict__ W1t) {
  const int b = blockIdx.x;
  const int tid = threadIdx.x;
  if (b < XBF_BLOCKS) {
    // x f32 -> xb bf16 (halves gather bytes)
    size_t idx = (size_t)b * 256 + tid;          // one float4 -> uint2 each
    float4 v = *(const float4*)(x + idx * 4);
    uint2 p;
    p.x = pack2(v.x, v.y);
    p.y = pack2(v.z, v.w);
    *(uint2*)(xb + idx * 4) = p;
  } else if (b < XBF_BLOCKS + STARTS_BLOCKS) {
    // starts[s] = first i with ids[i] >= s (ids sorted); starts[N_SEG] = N_INC
    int s = (b - XBF_BLOCKS) * 256 + tid;
    if (s > N_SEG) return;
    int lo = 0, hi = N_INC;
    while (lo < hi) {
      int mid = (lo + hi) >> 1;
      if (ids[mid] < s) lo = mid + 1; else hi = mid;
    }
    starts[s] = lo;
  } else {
    // W1 f32[256][512] -> W1t bf16[512][256]
    int idx = (b - XBF_BLOCKS - STARTS_BLOCKS) * 256 + tid;   // 0..32767
    int k  = idx >> 7;                           // 0..255
    int c4 = idx & 127;                          // float4 index along HIDDEN
    float4 v = *(const float4*)(W1 + (size_t)k * HIDDEN + c4 * 4);
    W1t[(c4 * 4 + 0) * IN_DIM + k] = f2bf(v.x);
    W1t[(c4 * 4 + 1) * IN_DIM + k] = f2bf(v.y);
    W1t[(c4 * 4 + 2) * IN_DIM + k] = f2bf(v.z);
    W1t[(c4 * 4 + 3) * IN_DIM + k] = f2bf(v.w);
  }
}

// ---------------- kernel 2: gather(bf16) + segment sum -> Zb bf16 ----------------
// Split-row: lanes 0-31 even incidences, lanes 32-63 odd; 16 B/lane (uint4) so one
// wave instruction covers TWO 512 B rows. Halves combined via shfl_xor(32).
// Pinned at the ~7.3 TB/s fabric/L3 roofline (rounds 3/4/7/8 all converge here).
#define ACC8(v)                                                        \
  acc0 += bflo((v).x); acc1 += bfhi((v).x);                            \
  acc2 += bflo((v).y); acc3 += bfhi((v).y);                            \
  acc4 += bflo((v).z); acc5 += bfhi((v).z);                            \
  acc6 += bflo((v).w); acc7 += bfhi((v).w);

__global__ void k_segsum(const unsigned short* __restrict__ xb, const int* __restrict__ nodes,
                         const int* __restrict__ starts, unsigned short* __restrict__ Zb) {
  int wave = threadIdx.x >> 6;
  int lane = threadIdx.x & 63;
  int s = blockIdx.x * 4 + wave;
  if (s >= N_SEG) return;
  const int beg = starts[s];
  const int end = starts[s + 1];
  const int half = lane >> 5;
  const int sl   = lane & 31;
  const unsigned short* base = xb + sl * 8;    // this lane's 16B slice within any row
  float acc0 = 0.f, acc1 = 0.f, acc2 = 0.f, acc3 = 0.f;
  float acc4 = 0.f, acc5 = 0.f, acc6 = 0.f, acc7 = 0.f;
  int j = beg + half;
  for (; j + 6 < end; j += 8) {               // 4 rows per half per iter
    int n0 = nodes[j], n1 = nodes[j + 2], n2 = nodes[j + 4], n3 = nodes[j + 6];
    uint4 v0 = *(const uint4*)(base + (size_t)n0 * IN_DIM);
    uint4 v1 = *(const uint4*)(base + (size_t)n1 * IN_DIM);
    uint4 v2 = *(const uint4*)(base + (size_t)n2 * IN_DIM);
    uint4 v3 = *(const uint4*)(base + (size_t)n3 * IN_DIM);
    ACC8(v0); ACC8(v1); ACC8(v2); ACC8(v3);
  }
  for (; j < end; j += 2) {
    int n0 = nodes[j];
    uint4 v0 = *(const uint4*)(base + (size_t)n0 * IN_DIM);
    ACC8(v0);
  }
  acc0 += __shfl_xor(acc0, 32, 64);
  acc1 += __shfl_xor(acc1, 32, 64);
  acc2 += __shfl_xor(acc2, 32, 64);
  acc3 += __shfl_xor(acc3, 32, 64);
  acc4 += __shfl_xor(acc4, 32, 64);
  acc5 += __shfl_xor(acc5, 32, 64);
  acc6 += __shfl_xor(acc6, 32, 64);
  acc7 += __shfl_xor(acc7, 32, 64);
  if (half == 0) {
    uint4 p;
    p.x = pack2(acc0, acc1);
    p.y = pack2(acc2, acc3);
    p.z = pack2(acc4, acc5);
    p.w = pack2(acc6, acc7);
    *(uint4*)(Zb + (size_t)s * IN_DIM + sl * 8) = p;
  }
}

// ---------------- kernel 3: MFMA MLP v8 — v5 + counted-vmcnt double-buffer (T3/T4) ----
// Block: 256 thr / 4 waves; block tile 256 rows; wave tile 64 rows x 64 cols (nt 0..7).
// A in registers (a[4][8] uint4, full K=256). B double-buffered in LDS (2 x 32 KB):
// per nt, issue next tile's 8 DMAs FIRST, then `s_waitcnt vmcnt(8)` (current tile's
// DMAs landed, next tile's stay in flight) + raw s_barrier + sched_barrier(0), then
// 128 MFMAs, then a second barrier (WAR guard before re-staging that buffer).
// Never drains vmcnt to 0 in the main loop (T4). 64 KB LDS -> 2 blocks/CU; all 391
// blocks co-resident. C/D layout (m89-verified): col = lane&15, row = (lane>>4)*4+e.
__global__ __launch_bounds__(256, 2) void k_mlp(
    const unsigned short* __restrict__ Zb, const unsigned short* __restrict__ W1t,
    const float* __restrict__ b1, const float* __restrict__ W2,
    const float* __restrict__ b2, float* __restrict__ out) {
  __shared__ __align__(16) unsigned short Bf[2][8][4][64][8];  // [buf][kc][cf][lane][e] 64 KB
  const int tid  = threadIdx.x;
  const int wave = tid >> 6;
  const int lane = tid & 63;
  const int m0   = blockIdx.x * 256 + wave * 64;

  // per-lane global source offset for B staging: col = c0 + wave*16 + (lane&15),
  // kk = kc*32 + (lane>>4)*8
  const unsigned short* wsrc = W1t + (size_t)(wave * 16 + (lane & 15)) * IN_DIM
                                   + (lane >> 4) * 8;

  // prologue: stage tile 0 into buffer 0 (8 DMAs, fire-and-forget)
  #pragma unroll
  for (int it = 0; it < 8; ++it)
    gload_lds16(wsrc + it * 32, &Bf[0][it][wave][lane][0]);

  // A fragments (overlap with tile-0 DMA latency): a[rf][kc],
  // lane l holds Z[m0+rf*16+(l&15)][kc*32+(l>>4)*8 ..+8]
  uint4 a[4][8];
  const int arow = m0 + (lane & 15);
  const int ak   = (lane >> 4) * 8;
  #pragma unroll
  for (int kc = 0; kc < 8; ++kc) {
    #pragma unroll
    for (int rf = 0; rf < 4; ++rf) {
      int row = arow + rf * 16;
      if (row < N_SEG)
        a[rf][kc] = *(const uint4*)(Zb + (size_t)row * IN_DIM + kc * 32 + ak);
      else
        a[rf][kc] = make_uint4(0u, 0u, 0u, 0u);
    }
  }

  float logit[4][4];
  #pragma unroll
  for (int rf = 0; rf < 4; ++rf)
    #pragma unroll
    for (int e = 0; e < 4; ++e) logit[rf][e] = 0.f;

  #pragma unroll
  for (int nt = 0; nt < 8; ++nt) {
    const int cur = nt & 1;
    // stage next tile into the other buffer (8 DMAs), then wait for CURRENT tile
    if (nt < 7) {
      const size_t csrc = (size_t)(nt + 1) * 64 * IN_DIM;
      #pragma unroll
      for (int it = 0; it < 8; ++it)
        gload_lds16(wsrc + csrc + it * 32, &Bf[cur ^ 1][it][wave][lane][0]);
      asm volatile("s_waitcnt vmcnt(8)" ::: "memory");  // current landed, next in flight
    } else {
      asm volatile("s_waitcnt vmcnt(0)" ::: "memory");  // epilogue: drain last tile
    }
    __builtin_amdgcn_s_barrier();          // all waves' current-tile DMAs landed
    __builtin_amdgcn_sched_barrier(0);     // no motion across the wait (rule #18)

    const int c0 = nt * 64;
    f32x4 acc[4][4];
    #pragma unroll
    for (int rf = 0; rf < 4; ++rf)
      #pragma unroll
      for (int cf = 0; cf < 4; ++cf) acc[rf][cf] = (f32x4){0.f, 0.f, 0.f, 0.f};

    #pragma unroll
    for (int kc = 0; kc < 8; ++kc) {
      #pragma unroll
      for (int cf = 0; cf < 4; ++cf) {
        bf16x8 bv = *(const bf16x8*)&Bf[cur][kc][cf][lane][0];
        #pragma unroll
        for (int rf = 0; rf < 4; ++rf) {
          bf16x8 av = __builtin_bit_cast(bf16x8, a[rf][kc]);
          acc[rf][cf] = __builtin_amdgcn_mfma_f32_16x16x32_bf16(av, bv, acc[rf][cf], 0, 0, 0);
        }
      }
    }

    // epilogue for this 64-col tile: bias + relu + dot with W2
    #pragma unroll
    for (int cf = 0; cf < 4; ++cf) {
      int cc = c0 + cf * 16 + (lane & 15);
      float bb = b1[cc];
      float w2 = W2[cc];
      #pragma unroll
      for (int rf = 0; rf < 4; ++rf)
        #pragma unroll
        for (int e = 0; e < 4; ++e) {
          float h = acc[rf][cf][e] + bb;
          h = h > 0.f ? h : 0.f;
          logit[rf][e] = fmaf(h, w2, logit[rf][e]);
        }
    }
    __builtin_amdgcn_s_barrier();          // WAR: all waves done reading Bf[cur]
  }

  // reduce over the 16 lanes of each column group (lane&15)
  #pragma unroll
  for (int rf = 0; rf < 4; ++rf)
    #pragma unroll
    for (int e = 0; e < 4; ++e) {
      float v = logit[rf][e];
      v += __shfl_xor(v, 1, 64);
      v += __shfl_xor(v, 2, 64);
      v += __shfl_xor(v, 4, 64);
      v += __shfl_xor(v, 8, 64);
      logit[rf][e] = v;
    }
  if ((lane & 15) == 0) {
    float bb2 = b2[0];
    #pragma unroll
    for (int rf = 0; rf < 4; ++rf)
      #pragma unroll
      for (int e = 0; e < 4; ++e) {
        int row = m0 + rf * 16 + (lane >> 4) * 4 + e;
        if (row < N_SEG)
          out[row] = 1.f / (1.f + expf(-(logit[rf][e] + bb2)));
      }
  }
}

extern "C" void kernel_launch(void* const* d_in, const int* in_sizes, int n_in,
                              void* d_out, int out_size, void* d_ws, size_t ws_size,
                              hipStream_t stream) {
  const float* x   = (const float*)d_in[0];
  const int* nodes = (const int*)d_in[1];
  const int* ids   = (const int*)d_in[2];
  const float* W1  = (const float*)d_in[4];
  const float* b1  = (const float*)d_in[5];
  const float* W2  = (const float*)d_in[6];
  const float* b2  = (const float*)d_in[7];
  float* out       = (float*)d_out;

  char* ws = (char*)d_ws;
  int* starts = (int*)ws;                                        // (N_SEG+1)*4 B
  size_t off = (((size_t)(N_SEG + 1) * sizeof(int)) + 1023) & ~(size_t)1023;
  unsigned short* Zb = (unsigned short*)(ws + off);              // 51.2 MB
  off += (size_t)N_NODES * IN_DIM * sizeof(unsigned short);
  off = (off + 1023) & ~(size_t)1023;
  unsigned short* W1t = (unsigned short*)(ws + off);             // 256 KB
  off += (size_t)HIDDEN * IN_DIM * sizeof(unsigned short);
  off = (off + 1023) & ~(size_t)1023;
  unsigned short* xb = (unsigned short*)(ws + off);              // 51.2 MB

  k_prep<<<XBF_BLOCKS + STARTS_BLOCKS + W1T_BLOCKS, 256, 0, stream>>>(
      x, xb, ids, starts, W1, W1t);
  k_segsum<<<(N_SEG + 3) / 4, 256, 0, stream>>>(xb, nodes, starts, Zb);
  k_mlp<<<(N_SEG + 255) / 256, 256, 0, stream>>>(Zb, W1t, b1, W2, b2, out);
}

// Round 16
// 149.593 us; speedup vs baseline: 1.1431x; 1.0157x over previous
//
#include <hip/hip_runtime.h>
#include <hip/hip_bf16.h>
#include <math.h>

#define N_NODES   100000
#define IN_DIM    256
#define HIDDEN    512
#define N_INC     1000000
#define N_SEG     100000

typedef __attribute__((ext_vector_type(8))) short bf16x8;
typedef __attribute__((ext_vector_type(4))) float f32x4;

__device__ __forceinline__ unsigned short f2bf(float f) {
  unsigned int u = __builtin_bit_cast(unsigned int, f);
  u += 0x7FFFu + ((u >> 16) & 1u);   // RNE
  return (unsigned short)(u >> 16);
}
__device__ __forceinline__ float bflo(unsigned int u) {   // low bf16 -> f32
  return __builtin_bit_cast(float, u << 16);
}
__device__ __forceinline__ float bfhi(unsigned int u) {   // high bf16 -> f32
  return __builtin_bit_cast(float, u & 0xFFFF0000u);
}
__device__ __forceinline__ unsigned pack2(float a, float b) {
  return (unsigned)f2bf(a) | ((unsigned)f2bf(b) << 16);
}

// async global->LDS DMA, 16 B per lane (1 KB per wave-instruction).
// LDS dest must be wave-uniform base + lane*16; global src may be per-lane.
__device__ __forceinline__ void gload_lds16(const void* g, void* l) {
  __builtin_amdgcn_global_load_lds(
      (const __attribute__((address_space(1))) unsigned int*)g,
      (__attribute__((address_space(3))) unsigned int*)l, 16, 0, 0);
}

#define XBF_BLOCKS    25000   // N_NODES*IN_DIM/4 float4s / 256 threads
#define STARTS_BLOCKS 391     // ceil((N_SEG+1)/256)
#define W1T_BLOCKS    128     // 32768 float4s / 256
#define BW2_BLOCKS    2       // 512 entries / 256

// ---------------- kernel 1: fused prep (xbf | seg_starts | w1t | bw2) ----------
__global__ void k_prep(const float* __restrict__ x, unsigned short* __restrict__ xb,
                       const int* __restrict__ ids, int* __restrict__ starts,
                       const float* __restrict__ W1, unsigned short* __restrict__ W1t,
                       const float* __restrict__ b1, const float* __restrict__ W2,
                       unsigned int* __restrict__ bw2) {
  const int b = blockIdx.x;
  const int tid = threadIdx.x;
  if (b < XBF_BLOCKS) {
    // x f32 -> xb bf16 (halves gather bytes)
    size_t idx = (size_t)b * 256 + tid;          // one float4 -> uint2 each
    float4 v = *(const float4*)(x + idx * 4);
    uint2 p;
    p.x = pack2(v.x, v.y);
    p.y = pack2(v.z, v.w);
    *(uint2*)(xb + idx * 4) = p;
  } else if (b < XBF_BLOCKS + STARTS_BLOCKS) {
    // starts[s] = first i with ids[i] >= s (ids sorted); starts[N_SEG] = N_INC
    int s = (b - XBF_BLOCKS) * 256 + tid;
    if (s > N_SEG) return;
    int lo = 0, hi = N_INC;
    while (lo < hi) {
      int mid = (lo + hi) >> 1;
      if (ids[mid] < s) lo = mid + 1; else hi = mid;
    }
    starts[s] = lo;
  } else if (b < XBF_BLOCKS + STARTS_BLOCKS + W1T_BLOCKS) {
    // W1 f32[256][512] -> W1t bf16[512][256]
    int idx = (b - XBF_BLOCKS - STARTS_BLOCKS) * 256 + tid;   // 0..32767
    int k  = idx >> 7;                           // 0..255
    int c4 = idx & 127;                          // float4 index along HIDDEN
    float4 v = *(const float4*)(W1 + (size_t)k * HIDDEN + c4 * 4);
    W1t[(c4 * 4 + 0) * IN_DIM + k] = f2bf(v.x);
    W1t[(c4 * 4 + 1) * IN_DIM + k] = f2bf(v.y);
    W1t[(c4 * 4 + 2) * IN_DIM + k] = f2bf(v.z);
    W1t[(c4 * 4 + 3) * IN_DIM + k] = f2bf(v.w);
  } else {
    // pack (b1[c], W2[c]) -> bw2[c] as bf16 pair (hoistable epilogue constants)
    int c = (b - XBF_BLOCKS - STARTS_BLOCKS - W1T_BLOCKS) * 256 + tid;  // 0..511
    if (c < HIDDEN) bw2[c] = pack2(b1[c], W2[c]);
  }
}

// ---------------- kernel 2: gather(bf16) + segment sum -> Zb bf16 ----------------
// Split-row: lanes 0-31 even incidences, lanes 32-63 odd; 16 B/lane (uint4) so one
// wave instruction covers TWO 512 B rows. Halves combined via shfl_xor(32).
// Pinned at the ~7.3 TB/s fabric/L3 roofline (rounds 3/4/7/8 all converge here).
#define ACC8(v)                                                        \
  acc0 += bflo((v).x); acc1 += bfhi((v).x);                            \
  acc2 += bflo((v).y); acc3 += bfhi((v).y);                            \
  acc4 += bflo((v).z); acc5 += bfhi((v).z);                            \
  acc6 += bflo((v).w); acc7 += bfhi((v).w);

__global__ void k_segsum(const unsigned short* __restrict__ xb, const int* __restrict__ nodes,
                         const int* __restrict__ starts, unsigned short* __restrict__ Zb) {
  int wave = threadIdx.x >> 6;
  int lane = threadIdx.x & 63;
  int s = blockIdx.x * 4 + wave;
  if (s >= N_SEG) return;
  const int beg = starts[s];
  const int end = starts[s + 1];
  const int half = lane >> 5;
  const int sl   = lane & 31;
  const unsigned short* base = xb + sl * 8;    // this lane's 16B slice within any row
  float acc0 = 0.f, acc1 = 0.f, acc2 = 0.f, acc3 = 0.f;
  float acc4 = 0.f, acc5 = 0.f, acc6 = 0.f, acc7 = 0.f;
  int j = beg + half;
  for (; j + 6 < end; j += 8) {               // 4 rows per half per iter
    int n0 = nodes[j], n1 = nodes[j + 2], n2 = nodes[j + 4], n3 = nodes[j + 6];
    uint4 v0 = *(const uint4*)(base + (size_t)n0 * IN_DIM);
    uint4 v1 = *(const uint4*)(base + (size_t)n1 * IN_DIM);
    uint4 v2 = *(const uint4*)(base + (size_t)n2 * IN_DIM);
    uint4 v3 = *(const uint4*)(base + (size_t)n3 * IN_DIM);
    ACC8(v0); ACC8(v1); ACC8(v2); ACC8(v3);
  }
  for (; j < end; j += 2) {
    int n0 = nodes[j];
    uint4 v0 = *(const uint4*)(base + (size_t)n0 * IN_DIM);
    ACC8(v0);
  }
  acc0 += __shfl_xor(acc0, 32, 64);
  acc1 += __shfl_xor(acc1, 32, 64);
  acc2 += __shfl_xor(acc2, 32, 64);
  acc3 += __shfl_xor(acc3, 32, 64);
  acc4 += __shfl_xor(acc4, 32, 64);
  acc5 += __shfl_xor(acc5, 32, 64);
  acc6 += __shfl_xor(acc6, 32, 64);
  acc7 += __shfl_xor(acc7, 32, 64);
  if (half == 0) {
    uint4 p;
    p.x = pack2(acc0, acc1);
    p.y = pack2(acc2, acc3);
    p.z = pack2(acc4, acc5);
    p.w = pack2(acc6, acc7);
    *(uint4*)(Zb + (size_t)s * IN_DIM + sl * 8) = p;
  }
}

// ---------------- kernel 3: MFMA MLP v9 — 8-wave blocks, dbuf DMA, hoisted epilogue ----
// Block: 512 thr / 8 waves; block tile 256 rows; wave tile 32 rows (rf=2); grid 391
// (same B-traffic as v5: 100 MB). Doubles waves/CU (8 -> 16 where 2 blocks) at zero
// traffic cost — co-residency was capped by grid size, not LDS. B double-buffered
// (2 x 32 KB); per phase each wave stages its kc=wave slice of the NEXT tile
// (4 DMAs, 16 B/lane), then counted `s_waitcnt vmcnt(4)` + raw barrier +
// sched_barrier(0). Epilogue constants hoisted to 32 regs (bw2) -> loop has no VMEM
// besides DMAs. C/D layout (m89-verified): col = lane&15, row = (lane>>4)*4 + e.
__global__ __launch_bounds__(512, 3) void k_mlp(
    const unsigned short* __restrict__ Zb, const unsigned short* __restrict__ W1t,
    const unsigned int* __restrict__ bw2, const float* __restrict__ b2,
    float* __restrict__ out) {
  __shared__ __align__(16) unsigned short Bf[2][8][4][64][8];  // [buf][kc][cf][lane][e] 64 KB
  const int tid  = threadIdx.x;
  const int wave = tid >> 6;         // 0..7
  const int lane = tid & 63;
  const int m0   = blockIdx.x * 256 + wave * 32;

  // per-lane global source base for this wave's B slice: kc = wave, cf = j:
  // src = W1t[(c0 + j*16 + (lane&15)) * 256 + wave*32 + (lane>>4)*8]
  const unsigned short* wsrc = W1t + (size_t)(lane & 15) * IN_DIM
                                   + wave * 32 + (lane >> 4) * 8;

  // prologue: stage tile 0 into buffer 0 (4 DMAs/wave, fire-and-forget)
  #pragma unroll
  for (int j = 0; j < 4; ++j)
    gload_lds16(wsrc + (size_t)(j * 16) * IN_DIM, &Bf[0][wave][j][lane][0]);

  // hoist epilogue constants: bw2r[nt*4+cf] = packed (b1,W2) at col
  // c = nt*64 + cf*16 + (lane&15)   (32 uint regs)
  unsigned int bw2r[32];
  #pragma unroll
  for (int i = 0; i < 32; ++i)
    bw2r[i] = bw2[(i >> 2) * 64 + (i & 3) * 16 + (lane & 15)];

  // A fragments (overlap with tile-0 DMA latency): a[rf][kc],
  // lane l holds Z[m0+rf*16+(l&15)][kc*32+(l>>4)*8 ..+8]
  uint4 a[2][8];
  const int arow = m0 + (lane & 15);
  const int ak   = (lane >> 4) * 8;
  #pragma unroll
  for (int kc = 0; kc < 8; ++kc) {
    #pragma unroll
    for (int rf = 0; rf < 2; ++rf) {
      int row = arow + rf * 16;
      if (row < N_SEG)
        a[rf][kc] = *(const uint4*)(Zb + (size_t)row * IN_DIM + kc * 32 + ak);
      else
        a[rf][kc] = make_uint4(0u, 0u, 0u, 0u);
    }
  }

  // b2 seeded once per 16-lane reduction group (summed exactly once by shfl-reduce)
  const float b2v = ((lane & 15) == 0) ? b2[0] : 0.f;
  float logit[2][4];
  #pragma unroll
  for (int rf = 0; rf < 2; ++rf)
    #pragma unroll
    for (int e = 0; e < 4; ++e) logit[rf][e] = b2v;

  #pragma unroll
  for (int nt = 0; nt < 8; ++nt) {
    const int cur = nt & 1;
    // stage NEXT tile's slice (4 DMAs), then wait for CURRENT tile only
    if (nt < 7) {
      const size_t csrc = (size_t)((nt + 1) * 64) * IN_DIM;
      #pragma unroll
      for (int j = 0; j < 4; ++j)
        gload_lds16(wsrc + csrc + (size_t)(j * 16) * IN_DIM, &Bf[cur ^ 1][wave][j][lane][0]);
      asm volatile("s_waitcnt vmcnt(4)" ::: "memory");  // current landed, next in flight
    } else {
      asm volatile("s_waitcnt vmcnt(0)" ::: "memory");  // epilogue: drain last tile
    }
    __builtin_amdgcn_s_barrier();          // all waves' current-tile DMAs landed
    __builtin_amdgcn_sched_barrier(0);     // no motion across the wait (rule #18)

    f32x4 acc[2][4];
    #pragma unroll
    for (int rf = 0; rf < 2; ++rf)
      #pragma unroll
      for (int cf = 0; cf < 4; ++cf) acc[rf][cf] = (f32x4){0.f, 0.f, 0.f, 0.f};

    #pragma unroll
    for (int kc = 0; kc < 8; ++kc) {
      #pragma unroll
      for (int cf = 0; cf < 4; ++cf) {
        bf16x8 bv = *(const bf16x8*)&Bf[cur][kc][cf][lane][0];
        #pragma unroll
        for (int rf = 0; rf < 2; ++rf) {
          bf16x8 av = __builtin_bit_cast(bf16x8, a[rf][kc]);
          acc[rf][cf] = __builtin_amdgcn_mfma_f32_16x16x32_bf16(av, bv, acc[rf][cf], 0, 0, 0);
        }
      }
    }

    // epilogue for this 64-col tile: bias + relu + dot with W2 (pure VALU, no VMEM)
    #pragma unroll
    for (int cf = 0; cf < 4; ++cf) {
      unsigned int bw = bw2r[nt * 4 + cf];
      float bb = bflo(bw);
      float w2 = bfhi(bw);
      #pragma unroll
      for (int rf = 0; rf < 2; ++rf)
        #pragma unroll
        for (int e = 0; e < 4; ++e) {
          float h = acc[rf][cf][e] + bb;
          h = h > 0.f ? h : 0.f;
          logit[rf][e] = fmaf(h, w2, logit[rf][e]);
        }
    }
    __builtin_amdgcn_s_barrier();          // WAR: all waves done reading Bf[cur]
  }

  // reduce over the 16 lanes of each column group (lane&15)
  #pragma unroll
  for (int rf = 0; rf < 2; ++rf)
    #pragma unroll
    for (int e = 0; e < 4; ++e) {
      float v = logit[rf][e];
      v += __shfl_xor(v, 1, 64);
      v += __shfl_xor(v, 2, 64);
      v += __shfl_xor(v, 4, 64);
      v += __shfl_xor(v, 8, 64);
      logit[rf][e] = v;
    }
  if ((lane & 15) == 0) {
    #pragma unroll
    for (int rf = 0; rf < 2; ++rf)
      #pragma unroll
      for (int e = 0; e < 4; ++e) {
        int row = m0 + rf * 16 + (lane >> 4) * 4 + e;
        if (row < N_SEG)
          out[row] = 1.f / (1.f + expf(-logit[rf][e]));
      }
  }
}

extern "C" void kernel_launch(void* const* d_in, const int* in_sizes, int n_in,
                              void* d_out, int out_size, void* d_ws, size_t ws_size,
                              hipStream_t stream) {
  const float* x   = (const float*)d_in[0];
  const int* nodes = (const int*)d_in[1];
  const int* ids   = (const int*)d_in[2];
  const float* W1  = (const float*)d_in[4];
  const float* b1  = (const float*)d_in[5];
  const float* W2  = (const float*)d_in[6];
  const float* b2  = (const float*)d_in[7];
  float* out       = (float*)d_out;

  char* ws = (char*)d_ws;
  int* starts = (int*)ws;                                        // (N_SEG+1)*4 B
  size_t off = (((size_t)(N_SEG + 1) * sizeof(int)) + 1023) & ~(size_t)1023;
  unsigned short* Zb = (unsigned short*)(ws + off);              // 51.2 MB
  off += (size_t)N_NODES * IN_DIM * sizeof(unsigned short);
  off = (off + 1023) & ~(size_t)1023;
  unsigned short* W1t = (unsigned short*)(ws + off);             // 256 KB
  off += (size_t)HIDDEN * IN_DIM * sizeof(unsigned short);
  off = (off + 1023) & ~(size_t)1023;
  unsigned int* bw2 = (unsigned int*)(ws + off);                 // 2 KB
  off += (size_t)HIDDEN * sizeof(unsigned int);
  off = (off + 1023) & ~(size_t)1023;
  unsigned short* xb = (unsigned short*)(ws + off);              // 51.2 MB

  k_prep<<<XBF_BLOCKS + STARTS_BLOCKS + W1T_BLOCKS + BW2_BLOCKS, 256, 0, stream>>>(
      x, xb, ids, starts, W1, W1t, b1, W2, bw2);
  k_segsum<<<(N_SEG + 3) / 4, 256, 0, stream>>>(xb, nodes, starts, Zb);
  k_mlp<<<(N_SEG + 255) / 256, 512, 0, stream>>>(Zb, W1t, bw2, b2, out);
}